// Round 11
// baseline (536.742 us; speedup 1.0000x reference)
//
#include <hip/hip_runtime.h>
#include <math.h>

#define NROWS  16384   // B*S
#define DMODEL 1024
#define NHEAD  16
#define HDIM   64
#define SEQ    4096
#define NBATCH 4
#define NBH    64      // NBATCH*NHEAD
#define SCHUNK 16      // split-K chunks over S for kv aggregation
#define M1     1048576u

typedef __attribute__((ext_vector_type(8)))  short bf16x8;
typedef __attribute__((ext_vector_type(4)))  float f32x4;
typedef __attribute__((ext_vector_type(16))) float f32x16;

#define VMCNT(N) asm volatile("s_waitcnt vmcnt(" #N ")" ::: "memory")
#define BAR() do { asm volatile("" ::: "memory"); __builtin_amdgcn_s_barrier(); \
                   asm volatile("" ::: "memory"); } while (0)

__device__ __forceinline__ unsigned short f2bf(float f) {
    unsigned u = __float_as_uint(f);
    u += 0x7FFFu + ((u >> 16) & 1u);   // round-to-nearest-even
    return (unsigned short)(u >> 16);
}
__device__ __forceinline__ float bf2f(unsigned short h) {
    return __uint_as_float((unsigned)h << 16);
}

__device__ __forceinline__ void gload16(const void* g, void* l) {
    __builtin_amdgcn_global_load_lds(
        (const __attribute__((address_space(1))) unsigned int*)g,
        (__attribute__((address_space(3))) unsigned int*)l, 16, 0, 0);
}

// ---------------------------------------------------------------------------
// split fp32 -> bf16 hi/lo pair (grid-stride, float4/ushort4 vectorized)
// ---------------------------------------------------------------------------
__global__ __launch_bounds__(256)
void split_pair(const float* __restrict__ a, unsigned short* __restrict__ hi,
                unsigned short* __restrict__ lo, int n4)
{
    int i = blockIdx.x * 256 + threadIdx.x;
    const int stride = gridDim.x * 256;
    for (; i < n4; i += stride) {
        const float4 v = ((const float4*)a)[i];
        ushort4 H, L;
        H.x = f2bf(v.x); L.x = f2bf(v.x - bf2f(H.x));
        H.y = f2bf(v.y); L.y = f2bf(v.y - bf2f(H.y));
        H.z = f2bf(v.z); L.z = f2bf(v.z - bf2f(H.z));
        H.w = f2bf(v.w); L.w = f2bf(v.w - bf2f(H.w));
        ((ushort4*)hi)[i] = H;
        ((ushort4*)lo)[i] = L;
    }
}

// 4 weight matrices -> hi block [4096][1024] rows [k|v|q|o], lo block same
__global__ __launch_bounds__(256)
void split_w4(const float* __restrict__ a0, const float* __restrict__ a1,
              const float* __restrict__ a2, const float* __restrict__ a3,
              unsigned short* __restrict__ hib, unsigned short* __restrict__ lob)
{
    const int y = blockIdx.y;   // 0=k 1=v 2=q 3=o
    const float* src = (y == 0) ? a0 : (y == 1) ? a1 : (y == 2) ? a2 : a3;
    const int i = blockIdx.x * 256 + threadIdx.x;   // 0..262143 (= 1M/4)
    const float4 v = ((const float4*)src)[i];
    ushort4 H, L;
    H.x = f2bf(v.x); L.x = f2bf(v.x - bf2f(H.x));
    H.y = f2bf(v.y); L.y = f2bf(v.y - bf2f(H.y));
    H.z = f2bf(v.z); L.z = f2bf(v.z - bf2f(H.z));
    H.w = f2bf(v.w); L.w = f2bf(v.w - bf2f(H.w));
    const size_t o = (size_t)y * M1 + (size_t)i * 4;
    *(ushort4*)&hib[o] = H;
    *(ushort4*)&lob[o] = L;
}

// ---------------------------------------------------------------------------
// Split-bf16 GEMM (NT), 32x32x16 MFMA, BK=16, 2 blocks/CU.
// C = A@W^T + bias, 3 MFMA passes (hh+hl+lh). 256x256 tile, 64 K-tiles of 16.
// 8 waves (2Mx4N), wave tile 128x64 = 4x2 frags of 32x32 (f32x16 acc).
// LDS 64 KB: 2 buffers x [Ah 8K|Al 8K|Wh 8K|Wl 8K]; chunk = 32 rows x 16 k
// stored as cells [kslot(2)][row(32)] x 8 bf16 -> frag read = chunk + lane*16B
// (linear, conflict-free); staged via per-lane-permuted global source
// (row = l&31, k = (l>>5)*8), LDS dest linear (gload_lds rule).
// Counted stream: tile kt ph0 stages A(kt+1) (after entry barrier, which
// seals kt-1's A readers); ph1 stages W(kt+2) after ph1 barrier (seals this
// tile's ph0 B-reads). Entry wait = vmcnt(2) (newest unit = W(kt+1) in
// flight), vmcnt(0) only at kt=63. 3 barriers/tile. T5 setprio, T1 swizzle.
// A/B frag layout: row=lane&31, kchunk=lane>>5 (symmetric with verified
// 16x16x32); C/D: col=lane&31, row=(reg&3)+8*(reg>>2)+4*(lane>>5) (m74/m101).
// MODE: 0 plain, 1 elu+1, 2 fused k|v (nb<4: k->C0/b0/elu, else v->C1/b1).
// ---------------------------------------------------------------------------
template<int MODE>
__global__ __launch_bounds__(512)
void gemm32(const unsigned short* __restrict__ Ah, const unsigned short* __restrict__ Al,
            const unsigned short* __restrict__ Wh, const unsigned short* __restrict__ Wl,
            const float* __restrict__ bias0, const float* __restrict__ bias1,
            float* __restrict__ C0, float* __restrict__ C1, int nbs)
{
    __shared__ unsigned short lds[32768];   // 2 buffers x 16384 ushorts (32KB each)
    const int t    = threadIdx.x;
    const int lane = t & 63;
    const int wv   = t >> 6;        // wave 0..7
    const int wr   = wv >> 2;       // M half   0..1 (128 rows)
    const int wcn  = wv & 3;        // N quarter 0..3 (64 cols)

    // XCD swizzle (bijective; grid divisible by 8)
    const int bid = blockIdx.x;
    const int swz = (bid & 7) * ((int)gridDim.x >> 3) + (bid >> 3);
    const int mb  = swz >> nbs;
    const int nb  = swz & ((1 << nbs) - 1);
    const int am0 = mb * 256;        // A panel row base
    const int bn0 = nb * 256;        // W panel row base (within passed W block)

    const int l31  = lane & 31;
    const int hi5  = lane >> 5;
    const unsigned fro = (unsigned)lane * 8u;   // frag read offset within chunk

    f32x16 acc[4][2];
#pragma unroll
    for (int i = 0; i < 4; ++i)
#pragma unroll
        for (int j = 0; j < 2; ++j)
#pragma unroll
            for (int e = 0; e < 16; ++e) acc[i][j][e] = 0.f;

    // stage A unit of tile kt (Ah+Al, 2 gload16); wave wv stages chunk wv
    auto stageA = [&](int kt) {
        const unsigned bb = ((unsigned)kt & 1u) * 16384u;
        const size_t g = (size_t)(am0 + wv * 32 + l31) * DMODEL + kt * 16 + hi5 * 8;
        gload16(Ah + g, (unsigned short*)&lds[bb + (unsigned)wv * 512u]);
        gload16(Al + g, (unsigned short*)&lds[bb + 4096u + (unsigned)wv * 512u]);
    };
    // stage W unit of tile kt (Wh+Wl, 2 gload16)
    auto stageW = [&](int kt) {
        const unsigned bb = ((unsigned)kt & 1u) * 16384u;
        const size_t g = (size_t)(bn0 + wv * 32 + l31) * DMODEL + kt * 16 + hi5 * 8;
        gload16(Wh + g, (unsigned short*)&lds[bb + 8192u  + (unsigned)wv * 512u]);
        gload16(Wl + g, (unsigned short*)&lds[bb + 12288u + (unsigned)wv * 512u]);
    };

    // prologue (FIFO): A(0), W(0), W(1)
    stageA(0); stageW(0); stageW(1);

#pragma unroll 2
    for (int kt = 0; kt < 64; ++kt) {
        if (kt < 63) { VMCNT(2); } else { VMCNT(0); }
        BAR();   // entry: tile kt data visible to all waves; seals kt-1 reads
        const unsigned bb = ((unsigned)kt & 1u) * 16384u;

        // ph0: B frags + A m0,m1; stage A(kt+1); barrier; 12 MFMA
        bf16x8 bh[2], bl[2];
#pragma unroll
        for (int ni = 0; ni < 2; ++ni) {
            const unsigned ch = (unsigned)(wcn * 2 + ni) * 512u;
            bh[ni] = *(const bf16x8*)&lds[bb + 8192u  + ch + fro];
            bl[ni] = *(const bf16x8*)&lds[bb + 12288u + ch + fro];
        }
        bf16x8 ah[2], al[2];
#pragma unroll
        for (int i2 = 0; i2 < 2; ++i2) {
            const unsigned ch = (unsigned)(wr * 4 + i2) * 512u;
            ah[i2] = *(const bf16x8*)&lds[bb + ch + fro];
            al[i2] = *(const bf16x8*)&lds[bb + 4096u + ch + fro];
        }
        if (kt + 1 < 64) stageA(kt + 1);
        __builtin_amdgcn_s_barrier();
        __builtin_amdgcn_s_setprio(1);
#pragma unroll
        for (int i2 = 0; i2 < 2; ++i2)
#pragma unroll
            for (int ni = 0; ni < 2; ++ni) {
                acc[i2][ni] = __builtin_amdgcn_mfma_f32_32x32x16_bf16(ah[i2], bh[ni], acc[i2][ni], 0, 0, 0);
                acc[i2][ni] = __builtin_amdgcn_mfma_f32_32x32x16_bf16(ah[i2], bl[ni], acc[i2][ni], 0, 0, 0);
                acc[i2][ni] = __builtin_amdgcn_mfma_f32_32x32x16_bf16(al[i2], bh[ni], acc[i2][ni], 0, 0, 0);
            }
        __builtin_amdgcn_s_setprio(0);

        // ph1: A m2,m3; barrier (seals all waves' ph0 B-reads); stage W(kt+2); 12 MFMA
#pragma unroll
        for (int i2 = 0; i2 < 2; ++i2) {
            const unsigned ch = (unsigned)(wr * 4 + 2 + i2) * 512u;
            ah[i2] = *(const bf16x8*)&lds[bb + ch + fro];
            al[i2] = *(const bf16x8*)&lds[bb + 4096u + ch + fro];
        }
        __builtin_amdgcn_s_barrier();
        if (kt + 2 < 64) stageW(kt + 2);
        __builtin_amdgcn_s_setprio(1);
#pragma unroll
        for (int i2 = 0; i2 < 2; ++i2)
#pragma unroll
            for (int ni = 0; ni < 2; ++ni) {
                acc[2 + i2][ni] = __builtin_amdgcn_mfma_f32_32x32x16_bf16(ah[i2], bh[ni], acc[2 + i2][ni], 0, 0, 0);
                acc[2 + i2][ni] = __builtin_amdgcn_mfma_f32_32x32x16_bf16(ah[i2], bl[ni], acc[2 + i2][ni], 0, 0, 0);
                acc[2 + i2][ni] = __builtin_amdgcn_mfma_f32_32x32x16_bf16(al[i2], bh[ni], acc[2 + i2][ni], 0, 0, 0);
            }
        __builtin_amdgcn_s_setprio(0);
    }

    // epilogue: C/D layout col=lane&31, row=(reg&3)+8*(reg>>2)+4*(lane>>5)
    bool elu = (MODE == 1);
    float* Cm = C0;
    const float* bm = bias0;
    int colb = bn0;                       // C col base = W row base (N=1024 modes)
    if (MODE == 2) {
        if (nb < 4) { elu = true; }
        else        { Cm = C1; bm = bias1; colb = (nb - 4) * 256; }
    }
    const int crow00 = am0 + wr * 128 + 4 * hi5;
#pragma unroll
    for (int ni = 0; ni < 2; ++ni) {
        const int col = colb + wcn * 64 + ni * 32 + l31;
        const float bv = bm[col];
#pragma unroll
        for (int mi = 0; mi < 4; ++mi) {
#pragma unroll
            for (int r = 0; r < 16; ++r) {
                const int row = crow00 + mi * 32 + (r & 3) + 8 * (r >> 2);
                float v = acc[mi][ni][r] + bv;
                if (elu) v = (v > 0.f) ? (v + 1.f) : __expf(v);  // elu(v)+1
                Cm[(size_t)row * DMODEL + col] = v;
            }
        }
    }
}

// ---------------------------------------------------------------------------
// kv partials: for (b,h,sc): kvp[d][e] = sum_{s in chunk} k[s,d]*v[s,e],
// ksp[d] = sum k[s,d]. Deterministic split-K, no atomics.
// ---------------------------------------------------------------------------
__global__ __launch_bounds__(512)
void kv_partial(const float* __restrict__ k, const float* __restrict__ v,
                float* __restrict__ kvp, float* __restrict__ ksp)
{
    __shared__ float Ks[32][64];
    __shared__ float Vs[32][64];
    const int t  = threadIdx.x;
    const int bh = blockIdx.x;
    const int b  = bh >> 4;
    const int h  = bh & 15;
    const int sc = blockIdx.y;
    const int d  = t & 63;
    const int e0 = (t >> 6) * 8;

    float acc[8];
#pragma unroll
    for (int j = 0; j < 8; ++j) acc[j] = 0.f;
    float ks = 0.f;

    const size_t rowbase = (size_t)b * SEQ;
    const int sbeg = sc * (SEQ / SCHUNK);       // 256 rows per chunk
    const int send = sbeg + (SEQ / SCHUNK);
    const int lrow = t >> 4;                    // staging: 0..31
    const int lc4  = (t & 15) * 4;

    for (int s0 = sbeg; s0 < send; s0 += 32) {
        const size_t g = (rowbase + s0 + lrow) * DMODEL + h * HDIM + lc4;
        *(float4*)&Ks[lrow][lc4] = *(const float4*)&k[g];
        *(float4*)&Vs[lrow][lc4] = *(const float4*)&v[g];
        __syncthreads();
#pragma unroll 8
        for (int sp = 0; sp < 32; ++sp) {
            const float kd = Ks[sp][d];
            if (t < 64) ks += Ks[sp][t];        // wave 0 only (wave-uniform branch)
            const float4 v0 = *(const float4*)&Vs[sp][e0 + 0];
            const float4 v1 = *(const float4*)&Vs[sp][e0 + 4];
            acc[0] = fmaf(kd, v0.x, acc[0]);  acc[1] = fmaf(kd, v0.y, acc[1]);
            acc[2] = fmaf(kd, v0.z, acc[2]);  acc[3] = fmaf(kd, v0.w, acc[3]);
            acc[4] = fmaf(kd, v1.x, acc[4]);  acc[5] = fmaf(kd, v1.y, acc[5]);
            acc[6] = fmaf(kd, v1.z, acc[6]);  acc[7] = fmaf(kd, v1.w, acc[7]);
        }
        __syncthreads();
    }

    const size_t base = ((size_t)sc * NBH + bh) * HDIM;
    float4 o0; o0.x = acc[0]; o0.y = acc[1]; o0.z = acc[2]; o0.w = acc[3];
    float4 o1; o1.x = acc[4]; o1.y = acc[5]; o1.z = acc[6]; o1.w = acc[7];
    *(float4*)&kvp[(base + d) * HDIM + e0 + 0] = o0;
    *(float4*)&kvp[(base + d) * HDIM + e0 + 4] = o1;
    if (t < 64) ksp[base + t] = ks;
}

__global__ __launch_bounds__(256)
void kv_reduce(const float* __restrict__ kvp, const float* __restrict__ ksp,
               float* __restrict__ kv, float* __restrict__ ksum)
{
    const int i = blockIdx.x * 256 + threadIdx.x;
    const int NKV = NBH * HDIM * HDIM;
    if (i < NKV) {
        float s = 0.f;
#pragma unroll
        for (int c = 0; c < SCHUNK; ++c) s += kvp[(size_t)c * NKV + i];
        kv[i] = s;
    }
    if (i < NBH * HDIM) {
        float s = 0.f;
#pragma unroll
        for (int c = 0; c < SCHUNK; ++c) s += ksp[(size_t)c * NBH * HDIM + i];
        ksum[i] = s;
    }
}

// ---------------------------------------------------------------------------
// att[s,e] = (sum_d q[s,d]*kv[d,e]) / (sum_d q[s,d]*ksum[d] + 1e-6),
// written directly as bf16 hi/lo (fused split for the final GEMM's A-operand).
// ---------------------------------------------------------------------------
__global__ __launch_bounds__(256)
void qkv_norm(const float* __restrict__ q, const float* __restrict__ kv,
              const float* __restrict__ ksum,
              unsigned short* __restrict__ ah, unsigned short* __restrict__ al)
{
    __shared__ float Qs[64][68];
    __shared__ float KVs[64][64];
    __shared__ float kss[64];
    const int t  = threadIdx.x;
    const int s0 = blockIdx.x * 64;
    const int b  = blockIdx.y;
    const int h  = blockIdx.z;
    const int bh = b * NHEAD + h;

#pragma unroll
    for (int i = 0; i < 4; ++i) {
        const int idx = i * 256 + t;
        const int row = idx >> 4;
        const int c4  = (idx & 15) * 4;
        const float4 vq = *(const float4*)&q[((size_t)b * SEQ + s0 + row) * DMODEL + h * HDIM + c4];
        *(float4*)&Qs[row][c4] = vq;
        *(float4*)&((float*)KVs)[idx * 4] = *(const float4*)&kv[(size_t)bh * HDIM * HDIM + idx * 4];
    }
    if (t < 64) kss[t] = ksum[(size_t)bh * HDIM + t];
    __syncthreads();

    const int r  = t >> 2;
    const int e0 = (t & 3) * 16;
    float out[16];
#pragma unroll
    for (int j = 0; j < 16; ++j) out[j] = 0.f;
    float nrm = 0.f;

#pragma unroll 8
    for (int d = 0; d < 64; ++d) {
        const float qd = Qs[r][d];
        nrm = fmaf(qd, kss[d], nrm);
        const float4 k0 = *(const float4*)&KVs[d][e0 + 0];
        const float4 k1 = *(const float4*)&KVs[d][e0 + 4];
        const float4 k2 = *(const float4*)&KVs[d][e0 + 8];
        const float4 k3 = *(const float4*)&KVs[d][e0 + 12];
        out[0]  = fmaf(qd, k0.x, out[0]);  out[1]  = fmaf(qd, k0.y, out[1]);
        out[2]  = fmaf(qd, k0.z, out[2]);  out[3]  = fmaf(qd, k0.w, out[3]);
        out[4]  = fmaf(qd, k1.x, out[4]);  out[5]  = fmaf(qd, k1.y, out[5]);
        out[6]  = fmaf(qd, k1.z, out[6]);  out[7]  = fmaf(qd, k1.w, out[7]);
        out[8]  = fmaf(qd, k2.x, out[8]);  out[9]  = fmaf(qd, k2.y, out[9]);
        out[10] = fmaf(qd, k2.z, out[10]); out[11] = fmaf(qd, k2.w, out[11]);
        out[12] = fmaf(qd, k3.x, out[12]); out[13] = fmaf(qd, k3.y, out[13]);
        out[14] = fmaf(qd, k3.z, out[14]); out[15] = fmaf(qd, k3.w, out[15]);
    }

    const float inv = 1.f / (nrm + 1e-6f);
    const size_t gbase = ((size_t)b * SEQ + s0 + r) * DMODEL + h * HDIM + e0;
#pragma unroll
    for (int g4 = 0; g4 < 4; ++g4) {
        ushort4 H, L;
        const float v0 = out[g4*4+0] * inv;
        const float v1 = out[g4*4+1] * inv;
        const float v2 = out[g4*4+2] * inv;
        const float v3 = out[g4*4+3] * inv;
        H.x = f2bf(v0); L.x = f2bf(v0 - bf2f(H.x));
        H.y = f2bf(v1); L.y = f2bf(v1 - bf2f(H.y));
        H.z = f2bf(v2); L.z = f2bf(v2 - bf2f(H.z));
        H.w = f2bf(v3); L.w = f2bf(v3 - bf2f(H.w));
        *(ushort4*)&ah[gbase + g4 * 4] = H;
        *(ushort4*)&al[gbase + g4 * 4] = L;
    }
}

// ---------------------------------------------------------------------------
extern "C" void kernel_launch(void* const* d_in, const int* in_sizes, int n_in,
                              void* d_out, int out_size, void* d_ws, size_t ws_size,
                              hipStream_t stream)
{
    const float* x  = (const float*)d_in[0];
    const float* Wq = (const float*)d_in[1];
    const float* bq = (const float*)d_in[2];
    const float* Wk = (const float*)d_in[3];
    const float* bk = (const float*)d_in[4];
    const float* Wv = (const float*)d_in[5];
    const float* bv = (const float*)d_in[6];
    const float* Wo = (const float*)d_in[7];
    const float* bo = (const float*)d_in[8];

    // workspace layout (~153 MB):
    unsigned short* xh  = (unsigned short*)d_ws;                   // [16384][1024] bf16 hi (x, then att)
    unsigned short* xl  = xh + (size_t)NROWS * DMODEL;             // lo
    unsigned short* whi = xl + (size_t)NROWS * DMODEL;             // W hi block [4096][1024] rows [k|v|q|o]
    unsigned short* wlo = whi + 4u * M1;                           // W lo block
    float* buf0 = (float*)(wlo + 4u * M1);                         // k, then q (fp32)
    float* kv   = buf0 + (size_t)NROWS * DMODEL;                   // [NBH][64][64]
    float* ksum = kv + NBH * HDIM * HDIM;                          // [NBH][64]
    float* kvp  = ksum + NBH * HDIM;                               // [SCHUNK][NBH][64][64]
    float* ksp  = kvp + (size_t)SCHUNK * NBH * HDIM * HDIM;        // [SCHUNK][NBH][64]
    float* vbuf = (float*)d_out;                                   // v lives in d_out (dead before final GEMM)

    const int n4x = NROWS * DMODEL / 4;

    // convert weights + x to bf16 hi/lo
    split_w4<<<dim3(1024, 4), 256, 0, stream>>>(Wk, Wv, Wq, Wo, whi, wlo);
    split_pair<<<4096, 256, 0, stream>>>(x, xh, xl, n4x);
    // fused: k = elu(x@Wk^T + bk)+1 -> buf0 ; v = x@Wv^T + bv -> d_out
    gemm32<2><<<512, 512, 0, stream>>>(xh, xl, whi, wlo, bk, bv, buf0, vbuf, 3);
    // kv, ksum (deterministic split-K + reduce)
    kv_partial<<<dim3(NBH, SCHUNK), 512, 0, stream>>>(buf0, vbuf, kvp, ksp);
    kv_reduce<<<1024, 256, 0, stream>>>(kvp, ksp, kv, ksum);
    // q = elu(x@Wq^T + bq)+1   (overwrites k)
    gemm32<1><<<256, 512, 0, stream>>>(xh, xl, whi + 2u * M1, wlo + 2u * M1,
                                       bq, nullptr, buf0, nullptr, 2);
    // att = (q@kv)/(q@ksum + 1e-6), fused bf16 hi/lo split (x split is dead)
    qkv_norm<<<dim3(SEQ / 64, NBATCH, NHEAD), 256, 0, stream>>>(buf0, kv, ksum, xh, xl);
    // out = att@Wo^T + bo  (overwrites v in d_out)
    gemm32<0><<<256, 512, 0, stream>>>(xh, xl, whi + 3u * M1, wlo + 3u * M1,
                                       bo, nullptr, (float*)d_out, nullptr, 2);
}